// Round 7
// baseline (1538.906 us; speedup 1.0000x reference)
//
#include <hip/hip_runtime.h>

// Problem constants: B=32, TX=TY=64, D=H=512, 4H=2048, V=32000.
typedef unsigned short ushort_t;
typedef __attribute__((ext_vector_type(8))) short short8;   // 8 bf16 = 4 VGPRs
typedef __attribute__((ext_vector_type(4))) float f32x4;    // MFMA 16x16 accumulator

__device__ __forceinline__ ushort_t f2bf(float x) {
  union { float f; unsigned int u; } v; v.f = x;
  unsigned int r = v.u + 0x7fffu + ((v.u >> 16) & 1u);  // RNE
  return (ushort_t)(r >> 16);
}
__device__ __forceinline__ float bf2f(ushort_t h) {
  union { unsigned int u; float f; } v; v.u = ((unsigned int)h) << 16; return v.f;
}
__device__ __forceinline__ void splitbf(float x, ushort_t& hi, ushort_t& lo) {
  hi = f2bf(x);
  lo = f2bf(x - bf2f(hi));
}
__device__ __forceinline__ float sigm(float x) { return 1.f / (1.f + expf(-x)); }
__device__ __forceinline__ f32x4 mfma16(short8 a, short8 b, f32x4 c) {
  return __builtin_amdgcn_mfma_f32_16x16x32_bf16(a, b, c, 0, 0, 0);
}

// R1-verified barrier over the 32-block bm-group. flags[i*32] = monotone
// arrival counter of block i (128B slots). Poisoned ws reads negative -> no
// init needed. h data uses write-through relaxed-agent stores into per-step
// buffers + never-reused consumer lines, so no release/acquire cache
// maintenance is needed; vmcnt(0) drains the stores to the coherence point
// before the flag store.
#define BAR_NB 64
__device__ __forceinline__ void gridbar(int* __restrict__ flags, int bid,
                                        int bm, int tid, int bar) {
  asm volatile("s_waitcnt vmcnt(0)" ::: "memory");  // h stores drained
  __syncthreads();
  if (tid == 0)
    __hip_atomic_store(&flags[bid * 32], bar, __ATOMIC_RELAXED,
                       __HIP_MEMORY_SCOPE_AGENT);
  if (tid < 32) {  // poll only the 32 blocks of this bm-group (ids 2k+bm)
    while (__hip_atomic_load(&flags[(2 * tid + bm) * 32], __ATOMIC_RELAXED,
                             __HIP_MEMORY_SCOPE_AGENT) < bar) {}
  }
  __syncthreads();
}

// ---------------------------------------------------------------------------
// Transpose + split: src fp32 [Krows][ld] (row offset k0) -> hi/lo bf16 [N][512]
// grid: (N/64, 512/64), block 256.
__global__ void __launch_bounds__(256) transpose_split(
    const float* __restrict__ src, int ld, int k0,
    ushort_t* __restrict__ hi, ushort_t* __restrict__ lo) {
  __shared__ float tile[64][65];
  const int n0 = blockIdx.x * 64, kb = blockIdx.y * 64;
  #pragma unroll
  for (int i = 0; i < 16; ++i) {
    int idx = i * 256 + threadIdx.x;
    int kk = idx >> 6, nn = idx & 63;
    tile[kk][nn] = src[(size_t)(k0 + kb + kk) * ld + n0 + nn];
  }
  __syncthreads();
  #pragma unroll
  for (int i = 0; i < 16; ++i) {
    int idx = i * 256 + threadIdx.x;
    int nn = idx >> 6, kk = idx & 63;
    float x = tile[kk][nn];
    ushort_t h, l; splitbf(x, h, l);
    size_t o = (size_t)(n0 + nn) * 512 + kb + kk;
    hi[o] = h; lo[o] = l;
  }
}

// ---------------------------------------------------------------------------
// Embedding gather + split: row m = t*32+b of A gets E[ids[b*T+t]].
__global__ void __launch_bounds__(128) embed_split(
    const int* __restrict__ ids, const float* __restrict__ E,
    ushort_t* __restrict__ Ahi, ushort_t* __restrict__ Alo, int T) {
  const int m = blockIdx.x;
  const int b = m & 31, t = m >> 5;
  const int id = ids[b * T + t];
  float4 v = ((const float4*)(E + (size_t)id * 512))[threadIdx.x];
  ushort_t h0, l0, h1, l1, h2, l2, h3, l3;
  splitbf(v.x, h0, l0); splitbf(v.y, h1, l1);
  splitbf(v.z, h2, l2); splitbf(v.w, h3, l3);
  ushort4 hv = make_ushort4(h0, h1, h2, h3);
  ushort4 lv = make_ushort4(l0, l1, l2, l3);
  ((ushort4*)(Ahi + (size_t)m * 512))[threadIdx.x] = hv;
  ((ushort4*)(Alo + (size_t)m * 512))[threadIdx.x] = lv;
}

// ---------------------------------------------------------------------------
// Split-bf16 3-pass GEMM: C[M][N] = (Ahi+Alo)[M][512] * (Bhi+Blo)^T[N][512] (+bias)
// Block tile 128x128, 4 waves of 64x64 (4x4 of 16x16x32 MFMA). K = 512 fixed.
// MFAST=0: m0 from blockIdx.y (original). MFAST=1: m0 from blockIdx.x so the
// 16 M-blocks sharing one B-tile are dispatch-adjacent (land on the 8 XCDs
// while the 256KB B-tile is L2-hot -> cuts pW re-fetch traffic from the MALL).
template <int MFAST>
__global__ void __launch_bounds__(256, 2) gemm_split_t(
    const ushort_t* __restrict__ Ahi, const ushort_t* __restrict__ Alo,
    const ushort_t* __restrict__ Bhi, const ushort_t* __restrict__ Blo,
    const float* __restrict__ bias, float* __restrict__ C, int M, int N) {
  __shared__ __align__(16) ushort_t lAh[128 * 64];
  __shared__ __align__(16) ushort_t lAl[128 * 64];
  __shared__ __align__(16) ushort_t lBh[128 * 64];
  __shared__ __align__(16) ushort_t lBl[128 * 64];
  const int tid = threadIdx.x;
  const int lane = tid & 63, w = tid >> 6;
  const int wm = (w >> 1) * 64, wn = (w & 1) * 64;
  const int lm = lane & 15, lq = lane >> 4;
  const int m0 = (MFAST ? blockIdx.x : blockIdx.y) * 128;
  const int n0 = (MFAST ? blockIdx.y : blockIdx.x) * 128;

  f32x4 acc[4][4];
  #pragma unroll
  for (int i = 0; i < 4; ++i)
    #pragma unroll
    for (int j = 0; j < 4; ++j)
      acc[i][j] = (f32x4){0.f, 0.f, 0.f, 0.f};

  for (int kc = 0; kc < 8; ++kc) {
    if (kc) __syncthreads();  // WAR: previous chunk's frag reads done
    #pragma unroll
    for (int i = 0; i < 4; ++i) {
      int cid = i * 256 + tid;            // 0..1023 16B-chunks per array
      int r = cid >> 3, c = cid & 7;
      int cs = c ^ (r & 7);
      size_t goffA = (size_t)(m0 + r) * 512 + kc * 64 + c * 8;
      size_t goffB = (size_t)(n0 + r) * 512 + kc * 64 + c * 8;
      *(uint4*)&lAh[r * 64 + cs * 8] = *(const uint4*)(Ahi + goffA);
      *(uint4*)&lAl[r * 64 + cs * 8] = *(const uint4*)(Alo + goffA);
      *(uint4*)&lBh[r * 64 + cs * 8] = *(const uint4*)(Bhi + goffB);
      *(uint4*)&lBl[r * 64 + cs * 8] = *(const uint4*)(Blo + goffB);
    }
    __syncthreads();
    #pragma unroll
    for (int ks = 0; ks < 2; ++ks) {
      short8 ah[4], al[4], bh[4], bl[4];
      #pragma unroll
      for (int t = 0; t < 4; ++t) {
        int ra = wm + t * 16 + lm;
        int ca = (ks * 4 + lq) ^ (ra & 7);
        ah[t] = *(const short8*)&lAh[ra * 64 + ca * 8];
        al[t] = *(const short8*)&lAl[ra * 64 + ca * 8];
        int rb = wn + t * 16 + lm;
        int cb = (ks * 4 + lq) ^ (rb & 7);
        bh[t] = *(const short8*)&lBh[rb * 64 + cb * 8];
        bl[t] = *(const short8*)&lBl[rb * 64 + cb * 8];
      }
      #pragma unroll
      for (int mt = 0; mt < 4; ++mt)
        #pragma unroll
        for (int nt = 0; nt < 4; ++nt) {
          acc[mt][nt] = mfma16(ah[mt], bh[nt], acc[mt][nt]);
          acc[mt][nt] = mfma16(ah[mt], bl[nt], acc[mt][nt]);
          acc[mt][nt] = mfma16(al[mt], bh[nt], acc[mt][nt]);
        }
    }
  }
  // epilogue: C/D layout col=lane&15, row=(lane>>4)*4+reg
  #pragma unroll
  for (int nt = 0; nt < 4; ++nt) {
    int col = n0 + wn + nt * 16 + lm;
    float bv = bias ? bias[col] : 0.f;
    #pragma unroll
    for (int mt = 0; mt < 4; ++mt) {
      int rbase = m0 + wm + mt * 16 + lq * 4;
      #pragma unroll
      for (int r = 0; r < 4; ++r)
        C[(size_t)(rbase + r) * N + col] = acc[mt][nt][r] + bv;
    }
  }
}

// ---------------------------------------------------------------------------
// Full enc+dec recurrence: 64 blocks x 256 thr, cooperative (co-residency),
// two independent 32-block barrier groups (bm=0 / bm=1 recurrences disjoint).
// Block = (bm in {0,1}: 16-batch tile) x (jg in [0,32): 16 H-cols). Wave = gate.
// Wh fragments live in registers. h[s] lives in a PER-STEP buffer (129 total):
// writers use write-through relaxed-agent atomic stores, readers use plain
// loads on never-before-touched lines -> no acquire fence / L2 inv / wbl2
// anywhere on the 128-step critical path. [R1-verified structure; only change
// vs R1: the xz prefetch is issued AFTER the barrier's flag store, so the
// arrive no longer waits for an HBM read latency inside vmcnt(0).]
__global__ void __launch_bounds__(256, 1) lstm_recurrence(
    const ushort_t* __restrict__ eWh_hi, const ushort_t* __restrict__ eWh_lo,
    const ushort_t* __restrict__ dWh_hi, const ushort_t* __restrict__ dWh_lo,
    const float* __restrict__ xz_enc, const float* __restrict__ xz_dec,
    const int* __restrict__ len_enc, const int* __restrict__ len_dec,
    ushort_t* __restrict__ hseq_hi, ushort_t* __restrict__ hseq_lo,
    ushort_t* __restrict__ hs_hi, ushort_t* __restrict__ hs_lo,
    int* __restrict__ flags) {
  const int tid = threadIdx.x;
  const int lane = tid & 63, g = tid >> 6;       // g = gate (i,j,f,o)
  const int lm = lane & 15, lq = lane >> 4;
  const int bm = blockIdx.x & 1, jg = blockIdx.x >> 1;

  __shared__ float z_x[4][16][17];
  __shared__ float c_st[16][17], h_st[16][17];

  const int bl = tid >> 4, nn = tid & 15;        // gate-phase mapping
  const int bglob = bm * 16 + bl;
  const int hcol = jg * 16 + nn;

  c_st[bl][nn] = 0.f; h_st[bl][nn] = 0.f;
  // h[0] = 0, write-through to LLC (step-0 buffer).
  __hip_atomic_store(&hseq_hi[bglob * 512 + hcol], (ushort_t)0,
                     __ATOMIC_RELAXED, __HIP_MEMORY_SCOPE_AGENT);
  __hip_atomic_store(&hseq_lo[bglob * 512 + hcol], (ushort_t)0,
                     __ATOMIC_RELAXED, __HIP_MEMORY_SCOPE_AGENT);
  const int lenE = len_enc[bglob], lenD = len_dec[bglob];

  // Preload encoder Wh fragments into registers.
  short8 fbh[16], fbl[16];
  const size_t browoff = (size_t)(g * 512 + jg * 16 + lm) * 512 + lq * 8;
  #pragma unroll
  for (int ks = 0; ks < 16; ++ks) {
    fbh[ks] = *(const short8*)(eWh_hi + browoff + ks * 32);
    fbl[ks] = *(const short8*)(eWh_lo + browoff + ks * 32);
  }

  // Prefetch step-0 gate inputs (independent of h -> issued before barrier).
  float pzi, pzj, pzf, pzo;
  {
    const size_t base = (size_t)bglob * 2048 + jg * 16 + nn;
    pzi = xz_enc[base];        pzj = xz_enc[base + 512];
    pzf = xz_enc[base + 1024]; pzo = xz_enc[base + 1536];
  }
  gridbar(flags, blockIdx.x, bm, tid, 1);   // h[0] visible everywhere

  const size_t arow = (size_t)(bm * 16 + lm) * 512 + lq * 8;

  #pragma unroll 1
  for (int s = 0; s < 128; ++s) {
    if (s == 64) {  // switch to decoder weights (uniform branch)
      #pragma unroll
      for (int ks = 0; ks < 16; ++ks) {
        fbh[ks] = *(const short8*)(dWh_hi + browoff + ks * 32);
        fbl[ks] = *(const short8*)(dWh_lo + browoff + ks * 32);
      }
    }
    const ushort_t* hh = hseq_hi + (size_t)s * 16384;       // 32*512
    const ushort_t* hl = hseq_lo + (size_t)s * 16384;
    ushort_t* ohh = hseq_hi + (size_t)(s + 1) * 16384;
    ushort_t* ohl = hseq_lo + (size_t)(s + 1) * 16384;

    // 3 independent accumulator chains: dep depth 16 instead of 48.
    f32x4 a0 = (f32x4){0.f, 0.f, 0.f, 0.f};
    f32x4 a1 = (f32x4){0.f, 0.f, 0.f, 0.f};
    f32x4 a2 = (f32x4){0.f, 0.f, 0.f, 0.f};
    #pragma unroll
    for (int ks = 0; ks < 16; ++ks) {
      short8 ah = *(const short8*)(hh + arow + ks * 32);
      short8 al = *(const short8*)(hl + arow + ks * 32);
      a0 = mfma16(ah, fbh[ks], a0);
      a1 = mfma16(ah, fbl[ks], a1);
      a2 = mfma16(al, fbh[ks], a2);
    }
    #pragma unroll
    for (int r = 0; r < 4; ++r)
      z_x[g][lq * 4 + r][lm] = a0[r] + a1[r] + a2[r];
    __syncthreads();

    {  // gate phase: thread (bl, nn) owns one (b, H-col) cell
      const bool isdec = s >= 64;
      const int t = isdec ? s - 64 : s;
      const int len = isdec ? lenD : lenE;
      float zi = z_x[0][bl][nn] + pzi;
      float zj = z_x[1][bl][nn] + pzj;
      float zf = z_x[2][bl][nn] + pzf;
      float zo = z_x[3][bl][nn] + pzo;
      float co = c_st[bl][nn], ho = h_st[bl][nn];
      float cn = co * sigm(zf + 1.0f) + sigm(zi) * tanhf(zj);  // forget bias 1.0
      float hn = tanhf(cn) * sigm(zo);
      bool msk = t < len;
      float ck = msk ? cn : co;
      float hk = msk ? hn : ho;
      c_st[bl][nn] = ck; h_st[bl][nn] = hk;
      ushort_t hi, lo;
      splitbf(hk, hi, lo);
      // Write-through to LLC (per-step buffer s+1); no fence needed.
      __hip_atomic_store(&ohh[bglob * 512 + hcol], hi, __ATOMIC_RELAXED,
                         __HIP_MEMORY_SCOPE_AGENT);
      __hip_atomic_store(&ohl[bglob * 512 + hcol], lo, __ATOMIC_RELAXED,
                         __HIP_MEMORY_SCOPE_AGENT);
      if (isdec) {  // emitted output: zeroed past length; row = b*64 + t
        float hv = msk ? hn : 0.f;
        splitbf(hv, hi, lo);
        hs_hi[((size_t)bglob * 64 + t) * 512 + hcol] = hi;
        hs_lo[((size_t)bglob * 64 + t) * 512 + hcol] = lo;
      }
    }
    if (s != 127) {
      // --- barrier with the xz prefetch moved AFTER the arrive ---
      // vmcnt(0) drains the h/hs stores (the ordering the protocol needs);
      // the flag store then publishes immediately. The 4 HBM prefetch loads
      // are issued after it and complete during the poll, so their ~900cyc
      // latency is off the serial arrive path (R1 paid it every step).
      asm volatile("s_waitcnt vmcnt(0)" ::: "memory");
      __syncthreads();
      if (tid == 0)
        __hip_atomic_store(&flags[blockIdx.x * 32], s + 2, __ATOMIC_RELAXED,
                           __HIP_MEMORY_SCOPE_AGENT);
      {
        const int sp = s + 1;
        const bool pd = sp >= 64;
        const float* xz = pd ? xz_dec : xz_enc;
        const int tp = pd ? sp - 64 : sp;
        const size_t base = ((size_t)tp * 32 + bglob) * 2048 + jg * 16 + nn;
        pzi = xz[base];        pzj = xz[base + 512];
        pzf = xz[base + 1024]; pzo = xz[base + 1536];
      }
      if (tid < 32) {
        while (__hip_atomic_load(&flags[(2 * tid + bm) * 32], __ATOMIC_RELAXED,
                                 __HIP_MEMORY_SCOPE_AGENT) < s + 2) {}
      }
      __syncthreads();
    }
  }
}

// ---------------------------------------------------------------------------
extern "C" void kernel_launch(void* const* d_in, const int* in_sizes, int n_in,
                              void* d_out, int out_size, void* d_ws, size_t ws_size,
                              hipStream_t stream) {
  (void)in_sizes; (void)n_in; (void)out_size; (void)ws_size;
  const int*   enc_ids = (const int*)d_in[0];
  const int*   dec_ids = (const int*)d_in[1];
  const int*   len_enc = (const int*)d_in[2];
  const int*   len_dec = (const int*)d_in[3];
  const float* E       = (const float*)d_in[4];
  const float* enc_W   = (const float*)d_in[5];
  const float* enc_b   = (const float*)d_in[6];
  const float* dec_W   = (const float*)d_in[7];
  const float* dec_b   = (const float*)d_in[8];
  const float* proj_W  = (const float*)d_in[9];

  char* w = (char*)d_ws;
  auto carve = [&](size_t bytes) -> char* {
    char* p = w; w += (bytes + 255) & ~(size_t)255; return p;
  };
  const size_t WSZ = 2048 * 512 * 2;  // [2048][512] bf16
  ushort_t* eWx_hi = (ushort_t*)carve(WSZ); ushort_t* eWx_lo = (ushort_t*)carve(WSZ);
  ushort_t* eWh_hi = (ushort_t*)carve(WSZ); ushort_t* eWh_lo = (ushort_t*)carve(WSZ);
  ushort_t* dWx_hi = (ushort_t*)carve(WSZ); ushort_t* dWx_lo = (ushort_t*)carve(WSZ);
  ushort_t* dWh_hi = (ushort_t*)carve(WSZ); ushort_t* dWh_lo = (ushort_t*)carve(WSZ);
  ushort_t* pW_hi  = (ushort_t*)carve((size_t)32000 * 512 * 2);
  ushort_t* pW_lo  = (ushort_t*)carve((size_t)32000 * 512 * 2);
  ushort_t* Ae_hi  = (ushort_t*)carve(WSZ); ushort_t* Ae_lo = (ushort_t*)carve(WSZ);
  ushort_t* Ad_hi  = (ushort_t*)carve(WSZ); ushort_t* Ad_lo = (ushort_t*)carve(WSZ);
  float* xz_enc = (float*)carve((size_t)64 * 32 * 2048 * 4);
  float* xz_dec = (float*)carve((size_t)64 * 32 * 2048 * 4);
  ushort_t* hs_hi = (ushort_t*)carve(WSZ); ushort_t* hs_lo = (ushort_t*)carve(WSZ);
  // Per-step h buffers: 129 x [32][512] bf16 per plane (R1-proven layout).
  ushort_t* hseq_hi = (ushort_t*)carve((size_t)129 * 32 * 512 * 2);
  ushort_t* hseq_lo = (ushort_t*)carve((size_t)129 * 32 * 512 * 2);
  int* flags = (int*)carve(BAR_NB * 32 * sizeof(int));

  dim3 blk(256);
  // Weight transpose+split (B^T layout [n][k] for contiguous MFMA B-fragments)
  transpose_split<<<dim3(32, 8),  blk, 0, stream>>>(enc_W, 2048, 0,   eWx_hi, eWx_lo);
  transpose_split<<<dim3(32, 8),  blk, 0, stream>>>(enc_W, 2048, 512, eWh_hi, eWh_lo);
  transpose_split<<<dim3(32, 8),  blk, 0, stream>>>(dec_W, 2048, 0,   dWx_hi, dWx_lo);
  transpose_split<<<dim3(32, 8),  blk, 0, stream>>>(dec_W, 2048, 512, dWh_hi, dWh_lo);
  transpose_split<<<dim3(500, 8), blk, 0, stream>>>(proj_W, 32000, 0, pW_hi, pW_lo);

  // Embedding gather+split (rows m = t*32+b)
  embed_split<<<2048, 128, 0, stream>>>(enc_ids, E, Ae_hi, Ae_lo, 64);
  embed_split<<<2048, 128, 0, stream>>>(dec_ids, E, Ad_hi, Ad_lo, 64);

  // Input-side gate pre-activations: xz[t][b][4H] = X @ W_x + b
  gemm_split_t<0><<<dim3(16, 16), blk, 0, stream>>>(Ae_hi, Ae_lo, eWx_hi, eWx_lo,
                                                    enc_b, xz_enc, 2048, 2048);
  gemm_split_t<0><<<dim3(16, 16), blk, 0, stream>>>(Ad_hi, Ad_lo, dWx_hi, dWx_lo,
                                                    dec_b, xz_dec, 2048, 2048);

  // Recurrence (cooperative launch for co-residency; custom barrier inside)
  void* args[] = { &eWh_hi, &eWh_lo, &dWh_hi, &dWh_lo,
                   (void*)&xz_enc, (void*)&xz_dec,
                   (void*)&len_enc, (void*)&len_dec,
                   &hseq_hi, &hseq_lo, &hs_hi, &hs_lo, &flags };
  hipLaunchCooperativeKernel((void*)lstm_recurrence, dim3(64), dim3(256),
                             args, 0, stream);

  // Vocab projection: out[b][t][v], row m = b*64+t matches hs layout.
  // MFAST grid: 16 M-blocks sharing each B-tile are dispatch-adjacent.
  const float* nobias = nullptr;
  gemm_split_t<1><<<dim3(16, 250), blk, 0, stream>>>(hs_hi, hs_lo, pW_hi, pW_lo,
                                                     nobias, (float*)d_out,
                                                     2048, 32000);
}

// Round 8
// 1513.868 us; speedup vs baseline: 1.0165x; 1.0165x over previous
//
#include <hip/hip_runtime.h>

// Problem constants: B=32, TX=TY=64, D=H=512, 4H=2048, V=32000.
typedef unsigned short ushort_t;
typedef __attribute__((ext_vector_type(8))) short short8;   // 8 bf16 = 4 VGPRs
typedef __attribute__((ext_vector_type(4))) float f32x4;    // MFMA 16x16 accumulator

__device__ __forceinline__ ushort_t f2bf(float x) {
  union { float f; unsigned int u; } v; v.f = x;
  unsigned int r = v.u + 0x7fffu + ((v.u >> 16) & 1u);  // RNE
  return (ushort_t)(r >> 16);
}
__device__ __forceinline__ float bf2f(ushort_t h) {
  union { unsigned int u; float f; } v; v.u = ((unsigned int)h) << 16; return v.f;
}
__device__ __forceinline__ void splitbf(float x, ushort_t& hi, ushort_t& lo) {
  hi = f2bf(x);
  lo = f2bf(x - bf2f(hi));
}
__device__ __forceinline__ float sigm(float x) { return 1.f / (1.f + expf(-x)); }
__device__ __forceinline__ f32x4 mfma16(short8 a, short8 b, f32x4 c) {
  return __builtin_amdgcn_mfma_f32_16x16x32_bf16(a, b, c, 0, 0, 0);
}

// Async global->LDS, 16B per lane. LDS dest is wave-uniform base + lane*16
// (hardware rule, m104); global src is per-lane.
__device__ __forceinline__ void gload16(const ushort_t* g, ushort_t* l) {
  __builtin_amdgcn_global_load_lds(
      (const __attribute__((address_space(1))) unsigned int*)g,
      (__attribute__((address_space(3))) unsigned int*)l, 16, 0, 0);
}

// R1-verified barrier over the 32-block bm-group. flags[i*32] = monotone
// arrival counter of block i (128B slots). Poisoned ws reads negative -> no
// init needed. h data uses write-through relaxed-agent stores into per-step
// buffers + never-reused consumer lines, so no release/acquire cache
// maintenance is needed; vmcnt(0) drains the stores to the coherence point
// before the flag store.
#define BAR_NB 64
__device__ __forceinline__ void gridbar(int* __restrict__ flags, int bid,
                                        int bm, int tid, int bar) {
  asm volatile("s_waitcnt vmcnt(0)" ::: "memory");  // h stores drained
  __syncthreads();
  if (tid == 0)
    __hip_atomic_store(&flags[bid * 32], bar, __ATOMIC_RELAXED,
                       __HIP_MEMORY_SCOPE_AGENT);
  if (tid < 32) {  // poll only the 32 blocks of this bm-group (ids 2k+bm)
    while (__hip_atomic_load(&flags[(2 * tid + bm) * 32], __ATOMIC_RELAXED,
                             __HIP_MEMORY_SCOPE_AGENT) < bar) {}
  }
  __syncthreads();
}

// ---------------------------------------------------------------------------
// Transpose + split: src fp32 [Krows][ld] (row offset k0) -> hi/lo bf16 [N][512]
// grid: (N/64, 512/64), block 256.
__global__ void __launch_bounds__(256) transpose_split(
    const float* __restrict__ src, int ld, int k0,
    ushort_t* __restrict__ hi, ushort_t* __restrict__ lo) {
  __shared__ float tile[64][65];
  const int n0 = blockIdx.x * 64, kb = blockIdx.y * 64;
  #pragma unroll
  for (int i = 0; i < 16; ++i) {
    int idx = i * 256 + threadIdx.x;
    int kk = idx >> 6, nn = idx & 63;
    tile[kk][nn] = src[(size_t)(k0 + kb + kk) * ld + n0 + nn];
  }
  __syncthreads();
  #pragma unroll
  for (int i = 0; i < 16; ++i) {
    int idx = i * 256 + threadIdx.x;
    int nn = idx >> 6, kk = idx & 63;
    float x = tile[kk][nn];
    ushort_t h, l; splitbf(x, h, l);
    size_t o = (size_t)(n0 + nn) * 512 + kb + kk;
    hi[o] = h; lo[o] = l;
  }
}

// ---------------------------------------------------------------------------
// Embedding gather + split: row m = t*32+b of A gets E[ids[b*T+t]].
__global__ void __launch_bounds__(128) embed_split(
    const int* __restrict__ ids, const float* __restrict__ E,
    ushort_t* __restrict__ Ahi, ushort_t* __restrict__ Alo, int T) {
  const int m = blockIdx.x;
  const int b = m & 31, t = m >> 5;
  const int id = ids[b * T + t];
  float4 v = ((const float4*)(E + (size_t)id * 512))[threadIdx.x];
  ushort_t h0, l0, h1, l1, h2, l2, h3, l3;
  splitbf(v.x, h0, l0); splitbf(v.y, h1, l1);
  splitbf(v.z, h2, l2); splitbf(v.w, h3, l3);
  ushort4 hv = make_ushort4(h0, h1, h2, h3);
  ushort4 lv = make_ushort4(l0, l1, l2, l3);
  ((ushort4*)(Ahi + (size_t)m * 512))[threadIdx.x] = hv;
  ((ushort4*)(Alo + (size_t)m * 512))[threadIdx.x] = lv;
}

// ---------------------------------------------------------------------------
// Split-bf16 3-pass GEMM: C[M][N] = (Ahi+Alo)[M][512] * (Bhi+Blo)^T[N][512] (+bias)
// Block tile 128x128, 4 waves of 64x64 (4x4 of 16x16x32 MFMA). K = 512 fixed.
// Staging uses global_load_lds width-16 (no VGPR round-trip): LDS dest is
// LINEAR (HW: wave-uniform base + lane*16), and the XOR bank swizzle is
// applied by PRE-SWIZZLING the global source column (c_src = c_lds ^ (r&7),
// involution) -> LDS contents identical to the old reg-staged version, so the
// swizzled read side and all numerics are unchanged.
// MFAST=1 swaps grid axes so the 16 M-blocks sharing one B-tile are
// dispatch-adjacent (projection B-tile L2 locality).
template <int MFAST>
__global__ void __launch_bounds__(256, 2) gemm_split_t(
    const ushort_t* __restrict__ Ahi, const ushort_t* __restrict__ Alo,
    const ushort_t* __restrict__ Bhi, const ushort_t* __restrict__ Blo,
    const float* __restrict__ bias, float* __restrict__ C, int M, int N) {
  __shared__ __align__(16) ushort_t lAh[128 * 64];
  __shared__ __align__(16) ushort_t lAl[128 * 64];
  __shared__ __align__(16) ushort_t lBh[128 * 64];
  __shared__ __align__(16) ushort_t lBl[128 * 64];
  const int tid = threadIdx.x;
  const int lane = tid & 63, w = tid >> 6;
  const int wm = (w >> 1) * 64, wn = (w & 1) * 64;
  const int lm = lane & 15, lq = lane >> 4;
  const int m0 = (MFAST ? blockIdx.x : blockIdx.y) * 128;
  const int n0 = (MFAST ? blockIdx.y : blockIdx.x) * 128;

  f32x4 acc[4][4];
  #pragma unroll
  for (int i = 0; i < 4; ++i)
    #pragma unroll
    for (int j = 0; j < 4; ++j)
      acc[i][j] = (f32x4){0.f, 0.f, 0.f, 0.f};

  for (int kc = 0; kc < 8; ++kc) {
    if (kc) __syncthreads();  // WAR: previous chunk's frag reads done
    #pragma unroll
    for (int i = 0; i < 4; ++i) {
      int cid = i * 256 + tid;            // 0..1023 16B-chunks per array
      int r = cid >> 3, cl = cid & 7;
      int csrc = cl ^ (r & 7);            // pre-swizzled source column
      size_t goffA = (size_t)(m0 + r) * 512 + kc * 64 + csrc * 8;
      size_t goffB = (size_t)(n0 + r) * 512 + kc * 64 + csrc * 8;
      int ldso = (i * 256 + w * 64) * 8;  // wave-uniform LDS base (ushorts)
      gload16(Ahi + goffA, lAh + ldso);   // lane offset = lane*16B (HW)
      gload16(Alo + goffA, lAl + ldso);
      gload16(Bhi + goffB, lBh + ldso);
      gload16(Blo + goffB, lBl + ldso);
    }
    __syncthreads();                      // drains vmcnt (loads landed in LDS)
    #pragma unroll
    for (int ks = 0; ks < 2; ++ks) {
      short8 ah[4], al[4], bh[4], bl[4];
      #pragma unroll
      for (int t = 0; t < 4; ++t) {
        int ra = wm + t * 16 + lm;
        int ca = (ks * 4 + lq) ^ (ra & 7);
        ah[t] = *(const short8*)&lAh[ra * 64 + ca * 8];
        al[t] = *(const short8*)&lAl[ra * 64 + ca * 8];
        int rb = wn + t * 16 + lm;
        int cb = (ks * 4 + lq) ^ (rb & 7);
        bh[t] = *(const short8*)&lBh[rb * 64 + cb * 8];
        bl[t] = *(const short8*)&lBl[rb * 64 + cb * 8];
      }
      #pragma unroll
      for (int mt = 0; mt < 4; ++mt)
        #pragma unroll
        for (int nt = 0; nt < 4; ++nt) {
          acc[mt][nt] = mfma16(ah[mt], bh[nt], acc[mt][nt]);
          acc[mt][nt] = mfma16(ah[mt], bl[nt], acc[mt][nt]);
          acc[mt][nt] = mfma16(al[mt], bh[nt], acc[mt][nt]);
        }
    }
  }
  // epilogue: C/D layout col=lane&15, row=(lane>>4)*4+reg
  #pragma unroll
  for (int nt = 0; nt < 4; ++nt) {
    int col = n0 + wn + nt * 16 + lm;
    float bv = bias ? bias[col] : 0.f;
    #pragma unroll
    for (int mt = 0; mt < 4; ++mt) {
      int rbase = m0 + wm + mt * 16 + lq * 4;
      #pragma unroll
      for (int r = 0; r < 4; ++r)
        C[(size_t)(rbase + r) * N + col] = acc[mt][nt][r] + bv;
    }
  }
}

// ---------------------------------------------------------------------------
// Full enc+dec recurrence: 64 blocks x 256 thr, cooperative (co-residency),
// two independent 32-block barrier groups (bm=0 / bm=1 recurrences disjoint).
// Block = (bm in {0,1}: 16-batch tile) x (jg in [0,32): 16 H-cols). Wave = gate.
// Wh fragments live in registers. h[s] lives in a PER-STEP buffer (129 total):
// writers use write-through relaxed-agent atomic stores, readers use plain
// loads on never-before-touched lines -> no acquire fence / L2 inv / wbl2
// anywhere on the 128-step critical path. [R1-EXACT structure, 898us verified;
// R7's prefetch-after-arrive was reverted (measured -13us regression).]
__global__ void __launch_bounds__(256, 1) lstm_recurrence(
    const ushort_t* __restrict__ eWh_hi, const ushort_t* __restrict__ eWh_lo,
    const ushort_t* __restrict__ dWh_hi, const ushort_t* __restrict__ dWh_lo,
    const float* __restrict__ xz_enc, const float* __restrict__ xz_dec,
    const int* __restrict__ len_enc, const int* __restrict__ len_dec,
    ushort_t* __restrict__ hseq_hi, ushort_t* __restrict__ hseq_lo,
    ushort_t* __restrict__ hs_hi, ushort_t* __restrict__ hs_lo,
    int* __restrict__ flags) {
  const int tid = threadIdx.x;
  const int lane = tid & 63, g = tid >> 6;       // g = gate (i,j,f,o)
  const int lm = lane & 15, lq = lane >> 4;
  const int bm = blockIdx.x & 1, jg = blockIdx.x >> 1;

  __shared__ float z_x[4][16][17];
  __shared__ float c_st[16][17], h_st[16][17];

  const int bl = tid >> 4, nn = tid & 15;        // gate-phase mapping
  const int bglob = bm * 16 + bl;
  const int hcol = jg * 16 + nn;

  c_st[bl][nn] = 0.f; h_st[bl][nn] = 0.f;
  // h[0] = 0, write-through to LLC (step-0 buffer).
  __hip_atomic_store(&hseq_hi[bglob * 512 + hcol], (ushort_t)0,
                     __ATOMIC_RELAXED, __HIP_MEMORY_SCOPE_AGENT);
  __hip_atomic_store(&hseq_lo[bglob * 512 + hcol], (ushort_t)0,
                     __ATOMIC_RELAXED, __HIP_MEMORY_SCOPE_AGENT);
  const int lenE = len_enc[bglob], lenD = len_dec[bglob];

  // Preload encoder Wh fragments into registers.
  short8 fbh[16], fbl[16];
  const size_t browoff = (size_t)(g * 512 + jg * 16 + lm) * 512 + lq * 8;
  #pragma unroll
  for (int ks = 0; ks < 16; ++ks) {
    fbh[ks] = *(const short8*)(eWh_hi + browoff + ks * 32);
    fbl[ks] = *(const short8*)(eWh_lo + browoff + ks * 32);
  }

  // Prefetch step-0 gate inputs (independent of h -> issued before barrier).
  float pzi, pzj, pzf, pzo;
  {
    const size_t base = (size_t)bglob * 2048 + jg * 16 + nn;
    pzi = xz_enc[base];        pzj = xz_enc[base + 512];
    pzf = xz_enc[base + 1024]; pzo = xz_enc[base + 1536];
  }
  gridbar(flags, blockIdx.x, bm, tid, 1);   // h[0] visible everywhere

  const size_t arow = (size_t)(bm * 16 + lm) * 512 + lq * 8;

  #pragma unroll 1
  for (int s = 0; s < 128; ++s) {
    if (s == 64) {  // switch to decoder weights (uniform branch)
      #pragma unroll
      for (int ks = 0; ks < 16; ++ks) {
        fbh[ks] = *(const short8*)(dWh_hi + browoff + ks * 32);
        fbl[ks] = *(const short8*)(dWh_lo + browoff + ks * 32);
      }
    }
    const ushort_t* hh = hseq_hi + (size_t)s * 16384;       // 32*512
    const ushort_t* hl = hseq_lo + (size_t)s * 16384;
    ushort_t* ohh = hseq_hi + (size_t)(s + 1) * 16384;
    ushort_t* ohl = hseq_lo + (size_t)(s + 1) * 16384;

    // 3 independent accumulator chains: dep depth 16 instead of 48.
    f32x4 a0 = (f32x4){0.f, 0.f, 0.f, 0.f};
    f32x4 a1 = (f32x4){0.f, 0.f, 0.f, 0.f};
    f32x4 a2 = (f32x4){0.f, 0.f, 0.f, 0.f};
    #pragma unroll
    for (int ks = 0; ks < 16; ++ks) {
      short8 ah = *(const short8*)(hh + arow + ks * 32);
      short8 al = *(const short8*)(hl + arow + ks * 32);
      a0 = mfma16(ah, fbh[ks], a0);
      a1 = mfma16(ah, fbl[ks], a1);
      a2 = mfma16(al, fbh[ks], a2);
    }
    #pragma unroll
    for (int r = 0; r < 4; ++r)
      z_x[g][lq * 4 + r][lm] = a0[r] + a1[r] + a2[r];
    __syncthreads();

    {  // gate phase: thread (bl, nn) owns one (b, H-col) cell
      const bool isdec = s >= 64;
      const int t = isdec ? s - 64 : s;
      const int len = isdec ? lenD : lenE;
      float zi = z_x[0][bl][nn] + pzi;
      float zj = z_x[1][bl][nn] + pzj;
      float zf = z_x[2][bl][nn] + pzf;
      float zo = z_x[3][bl][nn] + pzo;
      float co = c_st[bl][nn], ho = h_st[bl][nn];
      float cn = co * sigm(zf + 1.0f) + sigm(zi) * tanhf(zj);  // forget bias 1.0
      float hn = tanhf(cn) * sigm(zo);
      bool msk = t < len;
      float ck = msk ? cn : co;
      float hk = msk ? hn : ho;
      c_st[bl][nn] = ck; h_st[bl][nn] = hk;
      ushort_t hi, lo;
      splitbf(hk, hi, lo);
      // Write-through to LLC (per-step buffer s+1); no fence needed.
      __hip_atomic_store(&ohh[bglob * 512 + hcol], hi, __ATOMIC_RELAXED,
                         __HIP_MEMORY_SCOPE_AGENT);
      __hip_atomic_store(&ohl[bglob * 512 + hcol], lo, __ATOMIC_RELAXED,
                         __HIP_MEMORY_SCOPE_AGENT);
      if (isdec) {  // emitted output: zeroed past length; row = b*64 + t
        float hv = msk ? hn : 0.f;
        splitbf(hv, hi, lo);
        hs_hi[((size_t)bglob * 64 + t) * 512 + hcol] = hi;
        hs_lo[((size_t)bglob * 64 + t) * 512 + hcol] = lo;
      }
    }
    if (s != 127) {
      // Prefetch next step's gate inputs (h-independent), then barrier (R1).
      const int sp = s + 1;
      const bool pd = sp >= 64;
      const float* xz = pd ? xz_dec : xz_enc;
      const int tp = pd ? sp - 64 : sp;
      const size_t base = ((size_t)tp * 32 + bglob) * 2048 + jg * 16 + nn;
      pzi = xz[base];        pzj = xz[base + 512];
      pzf = xz[base + 1024]; pzo = xz[base + 1536];
      gridbar(flags, blockIdx.x, bm, tid, s + 2);
    }
  }
}

// ---------------------------------------------------------------------------
extern "C" void kernel_launch(void* const* d_in, const int* in_sizes, int n_in,
                              void* d_out, int out_size, void* d_ws, size_t ws_size,
                              hipStream_t stream) {
  (void)in_sizes; (void)n_in; (void)out_size; (void)ws_size;
  const int*   enc_ids = (const int*)d_in[0];
  const int*   dec_ids = (const int*)d_in[1];
  const int*   len_enc = (const int*)d_in[2];
  const int*   len_dec = (const int*)d_in[3];
  const float* E       = (const float*)d_in[4];
  const float* enc_W   = (const float*)d_in[5];
  const float* enc_b   = (const float*)d_in[6];
  const float* dec_W   = (const float*)d_in[7];
  const float* dec_b   = (const float*)d_in[8];
  const float* proj_W  = (const float*)d_in[9];

  char* w = (char*)d_ws;
  auto carve = [&](size_t bytes) -> char* {
    char* p = w; w += (bytes + 255) & ~(size_t)255; return p;
  };
  const size_t WSZ = 2048 * 512 * 2;  // [2048][512] bf16
  ushort_t* eWx_hi = (ushort_t*)carve(WSZ); ushort_t* eWx_lo = (ushort_t*)carve(WSZ);
  ushort_t* eWh_hi = (ushort_t*)carve(WSZ); ushort_t* eWh_lo = (ushort_t*)carve(WSZ);
  ushort_t* dWx_hi = (ushort_t*)carve(WSZ); ushort_t* dWx_lo = (ushort_t*)carve(WSZ);
  ushort_t* dWh_hi = (ushort_t*)carve(WSZ); ushort_t* dWh_lo = (ushort_t*)carve(WSZ);
  ushort_t* pW_hi  = (ushort_t*)carve((size_t)32000 * 512 * 2);
  ushort_t* pW_lo  = (ushort_t*)carve((size_t)32000 * 512 * 2);
  ushort_t* Ae_hi  = (ushort_t*)carve(WSZ); ushort_t* Ae_lo = (ushort_t*)carve(WSZ);
  ushort_t* Ad_hi  = (ushort_t*)carve(WSZ); ushort_t* Ad_lo = (ushort_t*)carve(WSZ);
  float* xz_enc = (float*)carve((size_t)64 * 32 * 2048 * 4);
  float* xz_dec = (float*)carve((size_t)64 * 32 * 2048 * 4);
  ushort_t* hs_hi = (ushort_t*)carve(WSZ); ushort_t* hs_lo = (ushort_t*)carve(WSZ);
  // Per-step h buffers: 129 x [32][512] bf16 per plane (R1-proven layout).
  ushort_t* hseq_hi = (ushort_t*)carve((size_t)129 * 32 * 512 * 2);
  ushort_t* hseq_lo = (ushort_t*)carve((size_t)129 * 32 * 512 * 2);
  int* flags = (int*)carve(BAR_NB * 32 * sizeof(int));

  dim3 blk(256);
  // Weight transpose+split (B^T layout [n][k] for contiguous MFMA B-fragments)
  transpose_split<<<dim3(32, 8),  blk, 0, stream>>>(enc_W, 2048, 0,   eWx_hi, eWx_lo);
  transpose_split<<<dim3(32, 8),  blk, 0, stream>>>(enc_W, 2048, 512, eWh_hi, eWh_lo);
  transpose_split<<<dim3(32, 8),  blk, 0, stream>>>(dec_W, 2048, 0,   dWx_hi, dWx_lo);
  transpose_split<<<dim3(32, 8),  blk, 0, stream>>>(dec_W, 2048, 512, dWh_hi, dWh_lo);
  transpose_split<<<dim3(500, 8), blk, 0, stream>>>(proj_W, 32000, 0, pW_hi, pW_lo);

  // Embedding gather+split (rows m = t*32+b)
  embed_split<<<2048, 128, 0, stream>>>(enc_ids, E, Ae_hi, Ae_lo, 64);
  embed_split<<<2048, 128, 0, stream>>>(dec_ids, E, Ad_hi, Ad_lo, 64);

  // Input-side gate pre-activations: xz[t][b][4H] = X @ W_x + b
  gemm_split_t<0><<<dim3(16, 16), blk, 0, stream>>>(Ae_hi, Ae_lo, eWx_hi, eWx_lo,
                                                    enc_b, xz_enc, 2048, 2048);
  gemm_split_t<0><<<dim3(16, 16), blk, 0, stream>>>(Ad_hi, Ad_lo, dWx_hi, dWx_lo,
                                                    dec_b, xz_dec, 2048, 2048);

  // Recurrence (cooperative launch for co-residency; custom barrier inside)
  void* args[] = { &eWh_hi, &eWh_lo, &dWh_hi, &dWh_lo,
                   (void*)&xz_enc, (void*)&xz_dec,
                   (void*)&len_enc, (void*)&len_dec,
                   &hseq_hi, &hseq_lo, &hs_hi, &hs_lo, &flags };
  hipLaunchCooperativeKernel((void*)lstm_recurrence, dim3(64), dim3(256),
                             args, 0, stream);

  // Vocab projection: out[b][t][v], row m = b*64+t matches hs layout.
  // MFAST grid: 16 M-blocks sharing each B-tile are dispatch-adjacent.
  const float* nobias = nullptr;
  gemm_split_t<1><<<dim3(16, 250), blk, 0, stream>>>(hs_hi, hs_lo, pW_hi, pW_lo,
                                                     nobias, (float*)d_out,
                                                     2048, 32000);
}

// Round 9
// 1428.519 us; speedup vs baseline: 1.0773x; 1.0597x over previous
//
#include <hip/hip_runtime.h>

// Problem constants: B=32, TX=TY=64, D=H=512, 4H=2048, V=32000.
typedef unsigned short ushort_t;
typedef _Float16 half_t;
typedef __attribute__((ext_vector_type(8))) short short8;     // 8 bf16 = 4 VGPRs
typedef __attribute__((ext_vector_type(8))) _Float16 half8;   // 8 fp16 = 4 VGPRs
typedef __attribute__((ext_vector_type(4))) float f32x4;      // MFMA 16x16 acc

__device__ __forceinline__ ushort_t f2bf(float x) {
  union { float f; unsigned int u; } v; v.f = x;
  unsigned int r = v.u + 0x7fffu + ((v.u >> 16) & 1u);  // RNE
  return (ushort_t)(r >> 16);
}
__device__ __forceinline__ float bf2f(ushort_t h) {
  union { unsigned int u; float f; } v; v.u = ((unsigned int)h) << 16; return v.f;
}
__device__ __forceinline__ void splitbf(float x, ushort_t& hi, ushort_t& lo) {
  hi = f2bf(x);
  lo = f2bf(x - bf2f(hi));
}
__device__ __forceinline__ float sigm(float x) { return 1.f / (1.f + expf(-x)); }
__device__ __forceinline__ f32x4 mfma16(short8 a, short8 b, f32x4 c) {
  return __builtin_amdgcn_mfma_f32_16x16x32_bf16(a, b, c, 0, 0, 0);
}
__device__ __forceinline__ f32x4 mfma16h(half8 a, half8 b, f32x4 c) {
  return __builtin_amdgcn_mfma_f32_16x16x32_f16(a, b, c, 0, 0, 0);
}

// Async global->LDS, 16B per lane. LDS dest is wave-uniform base + lane*16
// (hardware rule, m104); global src is per-lane.
__device__ __forceinline__ void gload16(const void* g, void* l) {
  __builtin_amdgcn_global_load_lds(
      (const __attribute__((address_space(1))) unsigned int*)g,
      (__attribute__((address_space(3))) unsigned int*)l, 16, 0, 0);
}

// R1-verified barrier over the 32-block bm-group. flags[i*32] = monotone
// arrival counter of block i (128B slots). Poisoned ws reads negative -> no
// init needed. h data uses write-through relaxed-agent stores into per-step
// buffers + never-reused consumer lines, so no release/acquire cache
// maintenance is needed; vmcnt(0) drains the stores to the coherence point
// before the flag store.
#define BAR_NB 64
__device__ __forceinline__ void gridbar(int* __restrict__ flags, int bid,
                                        int bm, int tid, int bar) {
  asm volatile("s_waitcnt vmcnt(0)" ::: "memory");  // h stores drained
  __syncthreads();
  if (tid == 0)
    __hip_atomic_store(&flags[bid * 32], bar, __ATOMIC_RELAXED,
                       __HIP_MEMORY_SCOPE_AGENT);
  if (tid < 32) {  // poll only the 32 blocks of this bm-group (ids 2k+bm)
    while (__hip_atomic_load(&flags[(2 * tid + bm) * 32], __ATOMIC_RELAXED,
                             __HIP_MEMORY_SCOPE_AGENT) < bar) {}
  }
  __syncthreads();
}

// ---------------------------------------------------------------------------
// Transpose + split: src fp32 [Krows][ld] (row offset k0) -> hi/lo bf16 [N][512]
// grid: (N/64, 512/64), block 256.
__global__ void __launch_bounds__(256) transpose_split(
    const float* __restrict__ src, int ld, int k0,
    ushort_t* __restrict__ hi, ushort_t* __restrict__ lo) {
  __shared__ float tile[64][65];
  const int n0 = blockIdx.x * 64, kb = blockIdx.y * 64;
  #pragma unroll
  for (int i = 0; i < 16; ++i) {
    int idx = i * 256 + threadIdx.x;
    int kk = idx >> 6, nn = idx & 63;
    tile[kk][nn] = src[(size_t)(k0 + kb + kk) * ld + n0 + nn];
  }
  __syncthreads();
  #pragma unroll
  for (int i = 0; i < 16; ++i) {
    int idx = i * 256 + threadIdx.x;
    int nn = idx >> 6, kk = idx & 63;
    float x = tile[kk][nn];
    ushort_t h, l; splitbf(x, h, l);
    size_t o = (size_t)(n0 + nn) * 512 + kb + kk;
    hi[o] = h; lo[o] = l;
  }
}

// ---------------------------------------------------------------------------
// Transpose to fp16 (single plane): src fp32 [512][ld] -> dst fp16 [N][512].
// Used for the vocab projection weight (final layer: fp16 precision suffices).
__global__ void __launch_bounds__(256) transpose_f16(
    const float* __restrict__ src, int ld, half_t* __restrict__ dst) {
  __shared__ float tile[64][65];
  const int n0 = blockIdx.x * 64, kb = blockIdx.y * 64;
  #pragma unroll
  for (int i = 0; i < 16; ++i) {
    int idx = i * 256 + threadIdx.x;
    int kk = idx >> 6, nn = idx & 63;
    tile[kk][nn] = src[(size_t)(kb + kk) * ld + n0 + nn];
  }
  __syncthreads();
  #pragma unroll
  for (int i = 0; i < 16; ++i) {
    int idx = i * 256 + threadIdx.x;
    int nn = idx >> 6, kk = idx & 63;
    dst[(size_t)(n0 + nn) * 512 + kb + kk] = (half_t)tile[kk][nn];
  }
}

// ---------------------------------------------------------------------------
// Embedding gather + split: row m = t*32+b of A gets E[ids[b*T+t]].
__global__ void __launch_bounds__(128) embed_split(
    const int* __restrict__ ids, const float* __restrict__ E,
    ushort_t* __restrict__ Ahi, ushort_t* __restrict__ Alo, int T) {
  const int m = blockIdx.x;
  const int b = m & 31, t = m >> 5;
  const int id = ids[b * T + t];
  float4 v = ((const float4*)(E + (size_t)id * 512))[threadIdx.x];
  ushort_t h0, l0, h1, l1, h2, l2, h3, l3;
  splitbf(v.x, h0, l0); splitbf(v.y, h1, l1);
  splitbf(v.z, h2, l2); splitbf(v.w, h3, l3);
  ushort4 hv = make_ushort4(h0, h1, h2, h3);
  ushort4 lv = make_ushort4(l0, l1, l2, l3);
  ((ushort4*)(Ahi + (size_t)m * 512))[threadIdx.x] = hv;
  ((ushort4*)(Alo + (size_t)m * 512))[threadIdx.x] = lv;
}

// ---------------------------------------------------------------------------
// Split-bf16 3-pass GEMM: C[M][N] = (Ahi+Alo)[M][512] * (Bhi+Blo)^T[N][512] (+bias)
// Block tile 128x128, 4 waves of 64x64 (4x4 of 16x16x32 MFMA). K = 512 fixed.
// Staging via global_load_lds width-16: LDS dest LINEAR, XOR bank swizzle done
// by pre-swizzling the global source column (involution) -> LDS contents and
// numerics identical to the reg-staged version. Used for the xz GEMMs (full
// precision: recurrence inputs, errors propagate 128 steps).
__global__ void __launch_bounds__(256, 2) gemm_split(
    const ushort_t* __restrict__ Ahi, const ushort_t* __restrict__ Alo,
    const ushort_t* __restrict__ Bhi, const ushort_t* __restrict__ Blo,
    const float* __restrict__ bias, float* __restrict__ C, int M, int N) {
  __shared__ __align__(16) ushort_t lAh[128 * 64];
  __shared__ __align__(16) ushort_t lAl[128 * 64];
  __shared__ __align__(16) ushort_t lBh[128 * 64];
  __shared__ __align__(16) ushort_t lBl[128 * 64];
  const int tid = threadIdx.x;
  const int lane = tid & 63, w = tid >> 6;
  const int wm = (w >> 1) * 64, wn = (w & 1) * 64;
  const int lm = lane & 15, lq = lane >> 4;
  const int m0 = blockIdx.y * 128, n0 = blockIdx.x * 128;

  f32x4 acc[4][4];
  #pragma unroll
  for (int i = 0; i < 4; ++i)
    #pragma unroll
    for (int j = 0; j < 4; ++j)
      acc[i][j] = (f32x4){0.f, 0.f, 0.f, 0.f};

  for (int kc = 0; kc < 8; ++kc) {
    if (kc) __syncthreads();  // WAR: previous chunk's frag reads done
    #pragma unroll
    for (int i = 0; i < 4; ++i) {
      int cid = i * 256 + tid;            // 0..1023 16B-chunks per array
      int r = cid >> 3, cl = cid & 7;
      int csrc = cl ^ (r & 7);            // pre-swizzled source column
      size_t goffA = (size_t)(m0 + r) * 512 + kc * 64 + csrc * 8;
      size_t goffB = (size_t)(n0 + r) * 512 + kc * 64 + csrc * 8;
      int ldso = (i * 256 + w * 64) * 8;  // wave-uniform LDS base (ushorts)
      gload16(Ahi + goffA, lAh + ldso);   // lane offset = lane*16B (HW)
      gload16(Alo + goffA, lAl + ldso);
      gload16(Bhi + goffB, lBh + ldso);
      gload16(Blo + goffB, lBl + ldso);
    }
    __syncthreads();                      // drains vmcnt (loads landed in LDS)
    #pragma unroll
    for (int ks = 0; ks < 2; ++ks) {
      short8 ah[4], al[4], bh[4], bl[4];
      #pragma unroll
      for (int t = 0; t < 4; ++t) {
        int ra = wm + t * 16 + lm;
        int ca = (ks * 4 + lq) ^ (ra & 7);
        ah[t] = *(const short8*)&lAh[ra * 64 + ca * 8];
        al[t] = *(const short8*)&lAl[ra * 64 + ca * 8];
        int rb = wn + t * 16 + lm;
        int cb = (ks * 4 + lq) ^ (rb & 7);
        bh[t] = *(const short8*)&lBh[rb * 64 + cb * 8];
        bl[t] = *(const short8*)&lBl[rb * 64 + cb * 8];
      }
      #pragma unroll
      for (int mt = 0; mt < 4; ++mt)
        #pragma unroll
        for (int nt = 0; nt < 4; ++nt) {
          acc[mt][nt] = mfma16(ah[mt], bh[nt], acc[mt][nt]);
          acc[mt][nt] = mfma16(ah[mt], bl[nt], acc[mt][nt]);
          acc[mt][nt] = mfma16(al[mt], bh[nt], acc[mt][nt]);
        }
    }
  }
  // epilogue: C/D layout col=lane&15, row=(lane>>4)*4+reg
  #pragma unroll
  for (int nt = 0; nt < 4; ++nt) {
    int col = n0 + wn + nt * 16 + lm;
    float bv = bias ? bias[col] : 0.f;
    #pragma unroll
    for (int mt = 0; mt < 4; ++mt) {
      int rbase = m0 + wm + mt * 16 + lq * 4;
      #pragma unroll
      for (int r = 0; r < 4; ++r)
        C[(size_t)(rbase + r) * N + col] = acc[mt][nt][r] + bv;
    }
  }
}

// ---------------------------------------------------------------------------
// FP16 single-pass GEMM for the vocab projection (final layer; fp16 input
// rounding gives ~1.3e-4 per-logit error std, absmax ~7e-4 < 1.64e-3 thr).
// C[M][N] = A[M][512] * B^T[N][512]. Same 128x128 tile / swizzle / staging as
// gemm_split but ONE plane per operand (32KB LDS) and 1 MFMA per frag pair
// (3x less MFMA work than the split path). Grid (M/128, N/128): the 16
// M-blocks sharing one B-tile are dispatch-adjacent (B-tile L2 locality).
__global__ void __launch_bounds__(256, 2) gemm_f16(
    const half_t* __restrict__ A, const half_t* __restrict__ Bm,
    float* __restrict__ C, int N) {
  __shared__ __align__(16) half_t lA[128 * 64];
  __shared__ __align__(16) half_t lB[128 * 64];
  const int tid = threadIdx.x;
  const int lane = tid & 63, w = tid >> 6;
  const int wm = (w >> 1) * 64, wn = (w & 1) * 64;
  const int lm = lane & 15, lq = lane >> 4;
  const int m0 = blockIdx.x * 128, n0 = blockIdx.y * 128;

  f32x4 acc[4][4];
  #pragma unroll
  for (int i = 0; i < 4; ++i)
    #pragma unroll
    for (int j = 0; j < 4; ++j)
      acc[i][j] = (f32x4){0.f, 0.f, 0.f, 0.f};

  for (int kc = 0; kc < 8; ++kc) {
    if (kc) __syncthreads();
    #pragma unroll
    for (int i = 0; i < 4; ++i) {
      int cid = i * 256 + tid;
      int r = cid >> 3, cl = cid & 7;
      int csrc = cl ^ (r & 7);
      size_t goffA = (size_t)(m0 + r) * 512 + kc * 64 + csrc * 8;
      size_t goffB = (size_t)(n0 + r) * 512 + kc * 64 + csrc * 8;
      int ldso = (i * 256 + w * 64) * 8;
      gload16(A + goffA, lA + ldso);
      gload16(Bm + goffB, lB + ldso);
    }
    __syncthreads();
    #pragma unroll
    for (int ks = 0; ks < 2; ++ks) {
      half8 a[4], b[4];
      #pragma unroll
      for (int t = 0; t < 4; ++t) {
        int ra = wm + t * 16 + lm;
        int ca = (ks * 4 + lq) ^ (ra & 7);
        a[t] = *(const half8*)&lA[ra * 64 + ca * 8];
        int rb = wn + t * 16 + lm;
        int cb = (ks * 4 + lq) ^ (rb & 7);
        b[t] = *(const half8*)&lB[rb * 64 + cb * 8];
      }
      #pragma unroll
      for (int mt = 0; mt < 4; ++mt)
        #pragma unroll
        for (int nt = 0; nt < 4; ++nt)
          acc[mt][nt] = mfma16h(a[mt], b[nt], acc[mt][nt]);
    }
  }
  #pragma unroll
  for (int nt = 0; nt < 4; ++nt) {
    int col = n0 + wn + nt * 16 + lm;
    #pragma unroll
    for (int mt = 0; mt < 4; ++mt) {
      int rbase = m0 + wm + mt * 16 + lq * 4;
      #pragma unroll
      for (int r = 0; r < 4; ++r)
        C[(size_t)(rbase + r) * N + col] = acc[mt][nt][r];
    }
  }
}

// ---------------------------------------------------------------------------
// Full enc+dec recurrence: 64 blocks x 256 thr, cooperative (co-residency),
// two independent 32-block barrier groups (bm=0 / bm=1 recurrences disjoint).
// Block = (bm in {0,1}: 16-batch tile) x (jg in [0,32): 16 H-cols). Wave = gate.
// Wh fragments live in registers. h[s] lives in a PER-STEP buffer (129 total):
// writers use write-through relaxed-agent atomic stores, readers use plain
// loads on never-before-touched lines -> no acquire fence / L2 inv / wbl2
// anywhere on the 128-step critical path. [R1-EXACT 898us-verified structure;
// only change: hs emitted as a single fp16 plane for the fp16 projection.]
__global__ void __launch_bounds__(256, 1) lstm_recurrence(
    const ushort_t* __restrict__ eWh_hi, const ushort_t* __restrict__ eWh_lo,
    const ushort_t* __restrict__ dWh_hi, const ushort_t* __restrict__ dWh_lo,
    const float* __restrict__ xz_enc, const float* __restrict__ xz_dec,
    const int* __restrict__ len_enc, const int* __restrict__ len_dec,
    ushort_t* __restrict__ hseq_hi, ushort_t* __restrict__ hseq_lo,
    half_t* __restrict__ hs_f16, int* __restrict__ flags) {
  const int tid = threadIdx.x;
  const int lane = tid & 63, g = tid >> 6;       // g = gate (i,j,f,o)
  const int lm = lane & 15, lq = lane >> 4;
  const int bm = blockIdx.x & 1, jg = blockIdx.x >> 1;

  __shared__ float z_x[4][16][17];
  __shared__ float c_st[16][17], h_st[16][17];

  const int bl = tid >> 4, nn = tid & 15;        // gate-phase mapping
  const int bglob = bm * 16 + bl;
  const int hcol = jg * 16 + nn;

  c_st[bl][nn] = 0.f; h_st[bl][nn] = 0.f;
  // h[0] = 0, write-through to LLC (step-0 buffer).
  __hip_atomic_store(&hseq_hi[bglob * 512 + hcol], (ushort_t)0,
                     __ATOMIC_RELAXED, __HIP_MEMORY_SCOPE_AGENT);
  __hip_atomic_store(&hseq_lo[bglob * 512 + hcol], (ushort_t)0,
                     __ATOMIC_RELAXED, __HIP_MEMORY_SCOPE_AGENT);
  const int lenE = len_enc[bglob], lenD = len_dec[bglob];

  // Preload encoder Wh fragments into registers.
  short8 fbh[16], fbl[16];
  const size_t browoff = (size_t)(g * 512 + jg * 16 + lm) * 512 + lq * 8;
  #pragma unroll
  for (int ks = 0; ks < 16; ++ks) {
    fbh[ks] = *(const short8*)(eWh_hi + browoff + ks * 32);
    fbl[ks] = *(const short8*)(eWh_lo + browoff + ks * 32);
  }

  // Prefetch step-0 gate inputs (independent of h -> issued before barrier).
  float pzi, pzj, pzf, pzo;
  {
    const size_t base = (size_t)bglob * 2048 + jg * 16 + nn;
    pzi = xz_enc[base];        pzj = xz_enc[base + 512];
    pzf = xz_enc[base + 1024]; pzo = xz_enc[base + 1536];
  }
  gridbar(flags, blockIdx.x, bm, tid, 1);   // h[0] visible everywhere

  const size_t arow = (size_t)(bm * 16 + lm) * 512 + lq * 8;

  #pragma unroll 1
  for (int s = 0; s < 128; ++s) {
    if (s == 64) {  // switch to decoder weights (uniform branch)
      #pragma unroll
      for (int ks = 0; ks < 16; ++ks) {
        fbh[ks] = *(const short8*)(dWh_hi + browoff + ks * 32);
        fbl[ks] = *(const short8*)(dWh_lo + browoff + ks * 32);
      }
    }
    const ushort_t* hh = hseq_hi + (size_t)s * 16384;       // 32*512
    const ushort_t* hl = hseq_lo + (size_t)s * 16384;
    ushort_t* ohh = hseq_hi + (size_t)(s + 1) * 16384;
    ushort_t* ohl = hseq_lo + (size_t)(s + 1) * 16384;

    // 3 independent accumulator chains: dep depth 16 instead of 48.
    f32x4 a0 = (f32x4){0.f, 0.f, 0.f, 0.f};
    f32x4 a1 = (f32x4){0.f, 0.f, 0.f, 0.f};
    f32x4 a2 = (f32x4){0.f, 0.f, 0.f, 0.f};
    #pragma unroll
    for (int ks = 0; ks < 16; ++ks) {
      short8 ah = *(const short8*)(hh + arow + ks * 32);
      short8 al = *(const short8*)(hl + arow + ks * 32);
      a0 = mfma16(ah, fbh[ks], a0);
      a1 = mfma16(ah, fbl[ks], a1);
      a2 = mfma16(al, fbh[ks], a2);
    }
    #pragma unroll
    for (int r = 0; r < 4; ++r)
      z_x[g][lq * 4 + r][lm] = a0[r] + a1[r] + a2[r];
    __syncthreads();

    {  // gate phase: thread (bl, nn) owns one (b, H-col) cell
      const bool isdec = s >= 64;
      const int t = isdec ? s - 64 : s;
      const int len = isdec ? lenD : lenE;
      float zi = z_x[0][bl][nn] + pzi;
      float zj = z_x[1][bl][nn] + pzj;
      float zf = z_x[2][bl][nn] + pzf;
      float zo = z_x[3][bl][nn] + pzo;
      float co = c_st[bl][nn], ho = h_st[bl][nn];
      float cn = co * sigm(zf + 1.0f) + sigm(zi) * tanhf(zj);  // forget bias 1.0
      float hn = tanhf(cn) * sigm(zo);
      bool msk = t < len;
      float ck = msk ? cn : co;
      float hk = msk ? hn : ho;
      c_st[bl][nn] = ck; h_st[bl][nn] = hk;
      ushort_t hi, lo;
      splitbf(hk, hi, lo);
      // Write-through to LLC (per-step buffer s+1); no fence needed.
      __hip_atomic_store(&ohh[bglob * 512 + hcol], hi, __ATOMIC_RELAXED,
                         __HIP_MEMORY_SCOPE_AGENT);
      __hip_atomic_store(&ohl[bglob * 512 + hcol], lo, __ATOMIC_RELAXED,
                         __HIP_MEMORY_SCOPE_AGENT);
      if (isdec) {  // emitted output: zeroed past length; row = b*64 + t
        float hv = msk ? hn : 0.f;
        hs_f16[((size_t)bglob * 64 + t) * 512 + hcol] = (half_t)hv;
      }
    }
    if (s != 127) {
      // Prefetch next step's gate inputs (h-independent), then barrier (R1).
      const int sp = s + 1;
      const bool pd = sp >= 64;
      const float* xz = pd ? xz_dec : xz_enc;
      const int tp = pd ? sp - 64 : sp;
      const size_t base = ((size_t)tp * 32 + bglob) * 2048 + jg * 16 + nn;
      pzi = xz[base];        pzj = xz[base + 512];
      pzf = xz[base + 1024]; pzo = xz[base + 1536];
      gridbar(flags, blockIdx.x, bm, tid, s + 2);
    }
  }
}

// ---------------------------------------------------------------------------
extern "C" void kernel_launch(void* const* d_in, const int* in_sizes, int n_in,
                              void* d_out, int out_size, void* d_ws, size_t ws_size,
                              hipStream_t stream) {
  (void)in_sizes; (void)n_in; (void)out_size; (void)ws_size;
  const int*   enc_ids = (const int*)d_in[0];
  const int*   dec_ids = (const int*)d_in[1];
  const int*   len_enc = (const int*)d_in[2];
  const int*   len_dec = (const int*)d_in[3];
  const float* E       = (const float*)d_in[4];
  const float* enc_W   = (const float*)d_in[5];
  const float* enc_b   = (const float*)d_in[6];
  const float* dec_W   = (const float*)d_in[7];
  const float* dec_b   = (const float*)d_in[8];
  const float* proj_W  = (const float*)d_in[9];

  char* w = (char*)d_ws;
  auto carve = [&](size_t bytes) -> char* {
    char* p = w; w += (bytes + 255) & ~(size_t)255; return p;
  };
  const size_t WSZ = 2048 * 512 * 2;  // [2048][512] bf16
  ushort_t* eWx_hi = (ushort_t*)carve(WSZ); ushort_t* eWx_lo = (ushort_t*)carve(WSZ);
  ushort_t* eWh_hi = (ushort_t*)carve(WSZ); ushort_t* eWh_lo = (ushort_t*)carve(WSZ);
  ushort_t* dWx_hi = (ushort_t*)carve(WSZ); ushort_t* dWx_lo = (ushort_t*)carve(WSZ);
  ushort_t* dWh_hi = (ushort_t*)carve(WSZ); ushort_t* dWh_lo = (ushort_t*)carve(WSZ);
  half_t*   pWf    = (half_t*)carve((size_t)32000 * 512 * 2);  // fp16 single
  ushort_t* Ae_hi  = (ushort_t*)carve(WSZ); ushort_t* Ae_lo = (ushort_t*)carve(WSZ);
  ushort_t* Ad_hi  = (ushort_t*)carve(WSZ); ushort_t* Ad_lo = (ushort_t*)carve(WSZ);
  float* xz_enc = (float*)carve((size_t)64 * 32 * 2048 * 4);
  float* xz_dec = (float*)carve((size_t)64 * 32 * 2048 * 4);
  half_t* hs_f16 = (half_t*)carve(WSZ);     // [2048][512] fp16 (row = b*64+t)
  // Per-step h buffers: 129 x [32][512] bf16 per plane (R1-proven layout).
  ushort_t* hseq_hi = (ushort_t*)carve((size_t)129 * 32 * 512 * 2);
  ushort_t* hseq_lo = (ushort_t*)carve((size_t)129 * 32 * 512 * 2);
  int* flags = (int*)carve(BAR_NB * 32 * sizeof(int));

  dim3 blk(256);
  // Weight transpose+split (B^T layout [n][k] for contiguous MFMA B-fragments)
  transpose_split<<<dim3(32, 8),  blk, 0, stream>>>(enc_W, 2048, 0,   eWx_hi, eWx_lo);
  transpose_split<<<dim3(32, 8),  blk, 0, stream>>>(enc_W, 2048, 512, eWh_hi, eWh_lo);
  transpose_split<<<dim3(32, 8),  blk, 0, stream>>>(dec_W, 2048, 0,   dWx_hi, dWx_lo);
  transpose_split<<<dim3(32, 8),  blk, 0, stream>>>(dec_W, 2048, 512, dWh_hi, dWh_lo);
  transpose_f16<<<dim3(500, 8),   blk, 0, stream>>>(proj_W, 32000, pWf);

  // Embedding gather+split (rows m = t*32+b)
  embed_split<<<2048, 128, 0, stream>>>(enc_ids, E, Ae_hi, Ae_lo, 64);
  embed_split<<<2048, 128, 0, stream>>>(dec_ids, E, Ad_hi, Ad_lo, 64);

  // Input-side gate pre-activations: xz[t][b][4H] = X @ W_x + b  (full
  // split-bf16 precision: these feed the 128-step recurrence).
  gemm_split<<<dim3(16, 16), blk, 0, stream>>>(Ae_hi, Ae_lo, eWx_hi, eWx_lo,
                                               enc_b, xz_enc, 2048, 2048);
  gemm_split<<<dim3(16, 16), blk, 0, stream>>>(Ad_hi, Ad_lo, dWx_hi, dWx_lo,
                                               dec_b, xz_dec, 2048, 2048);

  // Recurrence (cooperative launch for co-residency; custom barrier inside)
  void* args[] = { &eWh_hi, &eWh_lo, &dWh_hi, &dWh_lo,
                   (void*)&xz_enc, (void*)&xz_dec,
                   (void*)&len_enc, (void*)&len_dec,
                   &hseq_hi, &hseq_lo, &hs_f16, &flags };
  hipLaunchCooperativeKernel((void*)lstm_recurrence, dim3(64), dim3(256),
                             args, 0, stream);

  // Vocab projection (fp16 single-pass): out[b][t][v], rows match hs layout.
  gemm_f16<<<dim3(16, 250), blk, 0, stream>>>(hs_f16, pWf, (float*)d_out,
                                              32000);
}